// Round 3
// baseline (1621.077 us; speedup 1.0000x reference)
//
#include <hip/hip_runtime.h>
#include <cstddef>

#pragma clang fp contract(off)

#define B_    32
#define N_    16384
#define NPTS  (B_ * N_)              // 524288
#define FEATSZ (32 * 67 * 64 * 16)   // 2195456
#define GRID_COV 512

// ---- workspace layout ----
// f64 offsets (double*)
enum : int {
  D_X9    = 0,     // 9   (atomic -> zeroed)
  D_Y3SUM = 16,    // 64  (atomic -> zeroed)
  D_Y3SQ  = 80,    // 64  (atomic -> zeroed)
  D_MEAN1 = 144,   // 64  (overwritten by redS1)
  D_S1    = 208,   // 4096 (overwritten by redS1) -> ends 4304 doubles
};
// f32 offsets (float*), region starts at byte 65536
enum : int {
  F_M1   = 16384,  // 64
  F_R1   = 16448,  // 64
  F_M2   = 16512,  // 128
  F_R2   = 16640,  // 128
  F_M3   = 16768,  // 64
  F_R3   = 16832,  // 64
  F_W2T  = 16896,  // 8192 transposed w2 [c][o]
  F_TOPK = 25088,  // 2048*16 int32 -> ends float 57856 (byte 231424)
};
#define Y3_B     262144
#define S1PART_B 262144                      // overlays y3 (disjoint lifetime)
#define M1PART_B (262144 + GRID_COV * 4096 * 8)

// Faithful f32 layer-1 forward: identical expression used by k_cov64 and k_fwd
// so both produce bit-identical h1. Mirrors reference op order:
// y1 = (w.x) + b ; h1 = relu(((y1 - m) * rsqrt(v+eps)) * g + be)
__device__ __forceinline__ float h1_of(const float* __restrict__ w1,
                                       const float* __restrict__ b1,
                                       const float* __restrict__ g1,
                                       const float* __restrict__ be1,
                                       const float* __restrict__ fw, int c,
                                       float x0, float x1, float x2) {
  float s = w1[c*3+0] * x0;
  s = fmaf(w1[c*3+1], x1, s);
  s = fmaf(w1[c*3+2], x2, s);
  float y1 = s + b1[c];
  float t = y1 - fw[F_M1 + c];
  float u = t * fw[F_R1 + c];
  u = u * g1[c];
  u = u + be1[c];
  return fmaxf(u, 0.f);
}

// ---------------- K1: f64 mean + 3x3 second moment of x ----------------
__global__ __launch_bounds__(256) void k_xstats64(const float* __restrict__ x,
                                                  double* __restrict__ wd) {
  double a0=0,a1=0,a2=0,m00=0,m01=0,m02=0,m11=0,m12=0,m22=0;
  for (int p = blockIdx.x * 256 + threadIdx.x; p < NPTS; p += gridDim.x * 256) {
    int b = p >> 14, n = p & (N_ - 1);
    const float* xb = x + (size_t)b * 3 * N_ + n;
    double x0 = xb[0], x1 = xb[N_], x2 = xb[2 * N_];
    a0 += x0; a1 += x1; a2 += x2;
    m00 = fma(x0,x0,m00); m01 = fma(x0,x1,m01); m02 = fma(x0,x2,m02);
    m11 = fma(x1,x1,m11); m12 = fma(x1,x2,m12); m22 = fma(x2,x2,m22);
  }
  #pragma unroll
  for (int m = 32; m >= 1; m >>= 1) {
    a0 += __shfl_xor(a0, m); a1 += __shfl_xor(a1, m); a2 += __shfl_xor(a2, m);
    m00 += __shfl_xor(m00, m); m01 += __shfl_xor(m01, m); m02 += __shfl_xor(m02, m);
    m11 += __shfl_xor(m11, m); m12 += __shfl_xor(m12, m); m22 += __shfl_xor(m22, m);
  }
  if ((threadIdx.x & 63) == 0) {
    atomicAdd(&wd[D_X9+0], a0); atomicAdd(&wd[D_X9+1], a1); atomicAdd(&wd[D_X9+2], a2);
    atomicAdd(&wd[D_X9+3], m00); atomicAdd(&wd[D_X9+4], m01); atomicAdd(&wd[D_X9+5], m02);
    atomicAdd(&wd[D_X9+6], m11); atomicAdd(&wd[D_X9+7], m12); atomicAdd(&wd[D_X9+8], m22);
  }
}

// ---------------- K2: BN1 f32 coefficients from exact x-moments ----------------
__global__ void k_prep1(const float* __restrict__ w1, const float* __restrict__ b1,
                        double* __restrict__ wd, float* __restrict__ fw) {
  int c = threadIdx.x;
  if (c >= 64) return;
  const double inv = 1.0 / (double)NPTS;
  double mx0 = wd[0]*inv, mx1 = wd[1]*inv, mx2 = wd[2]*inv;
  double c00 = wd[3]*inv - mx0*mx0, c01 = wd[4]*inv - mx0*mx1, c02 = wd[5]*inv - mx0*mx2;
  double c11 = wd[6]*inv - mx1*mx1, c12 = wd[7]*inv - mx1*mx2, c22 = wd[8]*inv - mx2*mx2;
  double w0 = w1[c*3+0], w1_ = w1[c*3+1], w2_ = w1[c*3+2];
  double m1 = w0*mx0 + w1_*mx1 + w2_*mx2 + (double)b1[c];
  double var = w0*w0*c00 + w1_*w1_*c11 + w2_*w2_*c22
             + 2.0*(w0*w1_*c01 + w0*w2_*c02 + w1_*w2_*c12);
  fw[F_M1 + c] = (float)m1;
  float vpe = (float)var + 1e-5f;
  fw[F_R1 + c] = (float)(1.0 / sqrt((double)vpe));
}

// ------- K3: f64 second moment + sums of the ACTUAL f32 h1 values -------
__global__ __launch_bounds__(256) void k_cov64(const float* __restrict__ x,
                                               const float* __restrict__ w1,
                                               const float* __restrict__ b1,
                                               const float* __restrict__ g1,
                                               const float* __restrict__ be1,
                                               const float* __restrict__ fw,
                                               double* __restrict__ s1part,
                                               double* __restrict__ m1part) {
  __shared__ double tile[64 * 64];   // 32 KB: 64 points x 64 ch (f64 copies of f32 h1)
  const int tid = threadIdx.x;
  const int cover = tid >> 6, lane = tid & 63;
  const int ti = lane & 7, tj = lane >> 3;
  double acc[64];
  #pragma unroll
  for (int k = 0; k < 64; ++k) acc[k] = 0.0;
  double msum = 0.0;
  const int mc = tid & 63, mp0 = tid >> 6;

  for (int chunk = blockIdx.x; chunk < NPTS / 64; chunk += gridDim.x) {
    __syncthreads();
    {
      int pt = tid >> 2, q = tid & 3;
      int p = chunk * 64 + pt;
      int b = p >> 14, n = p & (N_ - 1);
      const float* xb = x + (size_t)b * 3 * N_ + n;
      float x0 = xb[0], x1 = xb[N_], x2 = xb[2 * N_];
      #pragma unroll
      for (int k = 0; k < 16; ++k) {
        int c = q * 16 + k;
        tile[pt * 64 + c] = (double)h1_of(w1, b1, g1, be1, fw, c, x0, x1, x2);
      }
    }
    __syncthreads();
    for (int pp = cover * 16; pp < cover * 16 + 16; ++pp) {
      const double* tp = tile + pp * 64;
      double a[8], bb[8];
      #pragma unroll
      for (int j = 0; j < 8; ++j) a[j] = tp[8 * ti + j];
      #pragma unroll
      for (int j = 0; j < 8; ++j) bb[j] = tp[8 * tj + j];
      #pragma unroll
      for (int r = 0; r < 8; ++r)
        #pragma unroll
        for (int q = 0; q < 8; ++q)
          acc[r*8+q] = fma(a[r], bb[q], acc[r*8+q]);
    }
    for (int pp = mp0; pp < 64; pp += 4) msum += tile[pp * 64 + mc];
  }
  __syncthreads();
  for (int cv = 0; cv < 4; ++cv) {
    if (cover == cv) {
      #pragma unroll
      for (int k = 0; k < 64; ++k) {
        int r = k >> 3, q = k & 7;
        int off = (8 * ti + r) * 64 + 8 * tj + q;
        if (cv == 0) tile[off] = acc[k]; else tile[off] += acc[k];
      }
    }
    __syncthreads();
  }
  for (int e = tid; e < 4096; e += 256) s1part[(size_t)blockIdx.x * 4096 + e] = tile[e];
  __syncthreads();
  tile[tid] = msum;
  __syncthreads();
  if (tid < 64)
    m1part[(size_t)blockIdx.x * 64 + tid] =
      tile[tid] + tile[64+tid] + tile[128+tid] + tile[192+tid];
}

// ---------------- K3b: sum partials ----------------
__global__ __launch_bounds__(256) void k_redS1(const double* __restrict__ s1part,
                                               const double* __restrict__ m1part,
                                               double* __restrict__ wd) {
  int tid = threadIdx.x;
  if (blockIdx.x < 16) {
    int e = blockIdx.x * 256 + tid;
    double s = 0.0;
    for (int b = 0; b < GRID_COV; ++b) s += s1part[(size_t)b * 4096 + e];
    wd[D_S1 + e] = s;
  } else if (tid < 64) {
    double s = 0.0;
    for (int b = 0; b < GRID_COV; ++b) s += m1part[(size_t)b * 64 + tid];
    wd[D_MEAN1 + tid] = s;
  }
}

// ---------------- K4: BN2 f32 coefficients + w2 transpose ----------------
__global__ __launch_bounds__(64) void k_prep2(const float* __restrict__ w2,
                                              const float* __restrict__ b2,
                                              double* __restrict__ wd,
                                              float* __restrict__ fw) {
  __shared__ double r1[64], r2[64];
  const int o = blockIdx.x, c = threadIdx.x;
  double wv = (double)w2[o * 64 + c];
  double inner = 0.0;
  for (int cc = 0; cc < 64; ++cc)
    inner = fma(wd[D_S1 + c * 64 + cc], (double)w2[o * 64 + cc], inner);
  r1[c] = wv * inner;
  r2[c] = wv * wd[D_MEAN1 + c];
  __syncthreads();
  for (int st = 32; st > 0; st >>= 1) {
    if (c < st) { r1[c] += r1[c + st]; r2[c] += r2[c + st]; }
    __syncthreads();
  }
  if (c == 0) {
    const double inv = 1.0 / (double)NPTS;
    double mraw = r2[0] * inv;
    double var = r1[0] * inv - mraw * mraw;
    fw[F_M2 + o] = (float)(mraw + (double)b2[o]);
    float vpe = (float)var + 1e-5f;
    fw[F_R2 + o] = (float)(1.0 / sqrt((double)vpe));
  }
  fw[F_W2T + c * 128 + o] = w2[o * 64 + c];
}

// -------- K5: faithful f32 forward x -> h1 -> h2 -> y3, store y3 --------
__global__ __launch_bounds__(256) void k_fwd(const float* __restrict__ x,
                                             const float* __restrict__ w1,
                                             const float* __restrict__ b1,
                                             const float* __restrict__ g1,
                                             const float* __restrict__ be1,
                                             const float* __restrict__ b2,
                                             const float* __restrict__ g2,
                                             const float* __restrict__ be2,
                                             const float* __restrict__ w3,
                                             const float* __restrict__ b3,
                                             const float* __restrict__ fw,
                                             float* __restrict__ y3out) {
  const int p = blockIdx.x * 256 + threadIdx.x;
  const int b = p >> 14, n = p & (N_ - 1);
  const float* xb = x + (size_t)b * 3 * N_ + n;
  const float x0 = xb[0], x1 = xb[N_], x2 = xb[2 * N_];
  float h1[64];
  #pragma unroll
  for (int c = 0; c < 64; ++c) h1[c] = h1_of(w1, b1, g1, be1, fw, c, x0, x1, x2);
  float acc[128];
  #pragma unroll
  for (int o = 0; o < 128; ++o) acc[o] = 0.f;
  const float* w2t = fw + F_W2T;
  #pragma unroll 2
  for (int c = 0; c < 64; ++c) {          // sequential ascending-c per output o
    const float hc = h1[c];
    const float* wc = w2t + c * 128;
    #pragma unroll
    for (int o = 0; o < 128; ++o) acc[o] = fmaf(wc[o], hc, acc[o]);
  }
  #pragma unroll
  for (int o = 0; o < 128; ++o) {
    float y2 = acc[o] + b2[o];
    float t = y2 - fw[F_M2 + o];
    float u = t * fw[F_R2 + o];
    u = u * g2[o];
    u = u + be2[o];
    acc[o] = fmaxf(u, 0.f);               // h2
  }
  float* yrow = y3out + (size_t)b * 64 * N_ + n;
  #pragma unroll 4
  for (int q = 0; q < 64; ++q) {
    const float* w = w3 + q * 128;
    float s = w[0] * acc[0];
    #pragma unroll
    for (int o = 1; o < 128; ++o) s = fmaf(w[o], acc[o], s);   // sequential ascending-o
    yrow[(size_t)q * N_] = s + b3[q];
  }
}

// ---------------- K5b: f64 per-channel sum/sumsq of stored f32 y3 ----------------
__global__ __launch_bounds__(256) void k_y3stats(const float* __restrict__ y3,
                                                 double* __restrict__ wd) {
  __shared__ double ss[256], sq[256];
  const int row = blockIdx.x, tid = threadIdx.x;
  const float4* y = (const float4*)(y3 + (size_t)row * N_);
  double s = 0.0, q = 0.0;
  for (int k = tid; k < N_ / 4; k += 256) {
    float4 v = y[k];
    double a = v.x, bb = v.y, c = v.z, d = v.w;
    s += a + bb + c + d;
    q = fma(a,a,q); q = fma(bb,bb,q); q = fma(c,c,q); q = fma(d,d,q);
  }
  ss[tid] = s; sq[tid] = q;
  __syncthreads();
  for (int st = 128; st > 0; st >>= 1) {
    if (tid < st) { ss[tid] += ss[tid + st]; sq[tid] += sq[tid + st]; }
    __syncthreads();
  }
  if (tid == 0) {
    atomicAdd(&wd[D_Y3SUM + (row & 63)], ss[0]);
    atomicAdd(&wd[D_Y3SQ  + (row & 63)], sq[0]);
  }
}

__global__ void k_prep3(double* __restrict__ wd, float* __restrict__ fw) {
  int o = threadIdx.x;
  if (o >= 64) return;
  const double inv = 1.0 / (double)NPTS;
  double m = wd[D_Y3SUM + o] * inv;
  double var = wd[D_Y3SQ + o] * inv - m * m;
  fw[F_M3 + o] = (float)m;
  float vpe = (float)var + 1e-5f;
  fw[F_R3 + o] = (float)(1.0 / sqrt((double)vpe));
}

// -------- K6: per-(b,c) top-16 smallest of sgn(g3)*y3, tie-break by index --------
__global__ __launch_bounds__(256) void k_topk(const float* __restrict__ y3,
                                              const float* __restrict__ g3,
                                              int* __restrict__ topk) {
  __shared__ float sval[256 * 16];
  __shared__ int   sidx[256 * 16];
  const int tid = threadIdx.x;
  const int row = blockIdx.x;
  const int c = row & 63;
  const float sgn = (g3[c] >= 0.f) ? 1.f : -1.f;
  const float4* y = (const float4*)(y3 + (size_t)row * N_);
  float val[16]; int idx[16];
  #pragma unroll
  for (int k = 0; k < 16; ++k) { val[k] = 3.0e38f; idx[k] = 0x7fffffff; }
  auto ins = [&](float v, int i) {
    if (v < val[15] || (v == val[15] && i < idx[15])) {
      float cv = v; int ci = i;
      #pragma unroll
      for (int k = 0; k < 16; ++k) {
        bool sw = (cv < val[k]) || (cv == val[k] && ci < idx[k]);
        float tv = val[k]; int tj = idx[k];
        if (sw) { val[k] = cv; idx[k] = ci; cv = tv; ci = tj; }
      }
    }
  };
  #pragma unroll 1
  for (int it = 0; it < 16; ++it) {
    int n4 = it * 256 + tid;
    float4 v = y[n4];
    int nb = n4 * 4;
    ins(sgn * v.x, nb + 0);
    ins(sgn * v.y, nb + 1);
    ins(sgn * v.z, nb + 2);
    ins(sgn * v.w, nb + 3);
  }
  #pragma unroll
  for (int k = 0; k < 16; ++k) { sval[tid*16+k] = val[k]; sidx[tid*16+k] = idx[k]; }
  __syncthreads();
  for (int s = 1; s < 256; s <<= 1) {
    if ((tid & (2 * s - 1)) == 0) {
      int pa = tid * 16, pb = (tid + s) * 16;
      int ia = 0, ib = 0;
      float mv[16]; int mi[16];
      #pragma unroll
      for (int k = 0; k < 16; ++k) {
        float va = sval[pa + ia]; int ja = sidx[pa + ia];
        float vb = sval[pb + ib]; int jb = sidx[pb + ib];
        bool ta = (va < vb) || (va == vb && ja < jb);
        mv[k] = ta ? va : vb; mi[k] = ta ? ja : jb;
        if (ta) ++ia; else ++ib;
      }
      #pragma unroll
      for (int k = 0; k < 16; ++k) { sval[pa + k] = mv[k]; sidx[pa + k] = mi[k]; }
    }
    __syncthreads();
  }
  if (tid < 16) topk[row * 16 + tid] = sidx[tid];
}

// ---------------- K7: gather feat (faithful BN3 apply) + idx as float ----------------
__global__ __launch_bounds__(256) void k_gather(const float* __restrict__ x,
                                                const float* __restrict__ fw,
                                                const float* __restrict__ g3,
                                                const float* __restrict__ be3,
                                                const float* __restrict__ y3,
                                                const int* __restrict__ topk,
                                                float* __restrict__ out) {
  __shared__ int s_i[16];
  __shared__ float s_m[64], s_r[64], s_g[64], s_b[64];
  const int tid = threadIdx.x;
  const int row = blockIdx.x;
  const int b = row >> 6, c = row & 63;
  if (tid < 16) s_i[tid] = topk[row * 16 + tid];
  if (tid < 64) {
    s_m[tid] = fw[F_M3 + tid]; s_r[tid] = fw[F_R3 + tid];
    s_g[tid] = g3[tid];        s_b[tid] = be3[tid];
  }
  __syncthreads();
  for (int t = tid; t < 67 * 16; t += 256) {
    int ch = t >> 4, n = t & 15, i = s_i[n];
    float v;
    if (ch < 3) {
      v = x[((size_t)b * 3 + ch) * N_ + i];
    } else {
      int c2 = ch - 3;
      float yv = y3[((size_t)b * 64 + c2) * N_ + i];
      float tt = yv - s_m[c2];
      float u = tt * s_r[c2];
      u = u * s_g[c2];
      v = u + s_b[c2];
    }
    out[(((size_t)b * 67 + ch) * 64 + c) * 16 + n] = v;
  }
  if (tid < 48) {
    int ch = tid >> 4, n = tid & 15;
    out[FEATSZ + (((size_t)b * 3 + ch) * 64 + c) * 16 + n] = (float)s_i[n];
  }
}

extern "C" void kernel_launch(void* const* d_in, const int* in_sizes, int n_in,
                              void* d_out, int out_size, void* d_ws, size_t ws_size,
                              hipStream_t stream) {
  const float* x   = (const float*)d_in[0];
  const float* w1  = (const float*)d_in[1];
  const float* b1  = (const float*)d_in[2];
  const float* be1 = (const float*)d_in[4];
  const float* g1  = (const float*)d_in[3];
  const float* w2  = (const float*)d_in[5];
  const float* b2  = (const float*)d_in[6];
  const float* g2  = (const float*)d_in[7];
  const float* be2 = (const float*)d_in[8];
  const float* w3  = (const float*)d_in[9];
  const float* b3  = (const float*)d_in[10];
  const float* g3  = (const float*)d_in[11];
  const float* be3 = (const float*)d_in[12];
  double* wd = (double*)d_ws;
  float*  fw = (float*)d_ws;
  float*  out = (float*)d_out;
  int* topk = (int*)(fw + F_TOPK);
  double* s1part = (double*)((char*)d_ws + S1PART_B);
  double* m1part = (double*)((char*)d_ws + M1PART_B);
  float*  y3     = (float*)((char*)d_ws + Y3_B);

  hipMemsetAsync(d_ws, 0, 1216, stream);   // zero D_X9 + D_Y3SUM + D_Y3SQ
  k_xstats64<<<512, 256, 0, stream>>>(x, wd);
  k_prep1   <<<1, 64, 0, stream>>>(w1, b1, wd, fw);
  k_cov64   <<<GRID_COV, 256, 0, stream>>>(x, w1, b1, g1, be1, fw, s1part, m1part);
  k_redS1   <<<17, 256, 0, stream>>>(s1part, m1part, wd);
  k_prep2   <<<128, 64, 0, stream>>>(w2, b2, wd, fw);
  k_fwd     <<<NPTS / 256, 256, 0, stream>>>(x, w1, b1, g1, be1, b2, g2, be2, w3, b3, fw, y3);
  k_y3stats <<<B_ * 64, 256, 0, stream>>>(y3, wd);
  k_prep3   <<<1, 64, 0, stream>>>(wd, fw);
  k_topk    <<<B_ * 64, 256, 0, stream>>>(y3, g3, topk);
  k_gather  <<<B_ * 64, 256, 0, stream>>>(x, fw, g3, be3, y3, topk, out);
  (void)in_sizes; (void)n_in; (void)out_size; (void)ws_size;
}

// Round 4
// 917.621 us; speedup vs baseline: 1.7666x; 1.7666x over previous
//
#include <hip/hip_runtime.h>
#include <cstddef>

#pragma clang fp contract(off)

#define B_    32
#define N_    16384
#define NPTS  (B_ * N_)              // 524288
#define FEATSZ (32 * 67 * 64 * 16)   // 2195456
#define GRID_COV 512

// ---- workspace layout ----
// f64 offsets (double*)
enum : int {
  D_X9    = 0,     // 9   (atomic -> zeroed)
  D_Y3SUM = 16,    // 64  (atomic -> zeroed)
  D_Y3SQ  = 80,    // 64  (atomic -> zeroed)
  D_MEAN1 = 144,   // 64  (overwritten by redS1)
  D_S1    = 208,   // 4096 (overwritten by redS1) -> ends 4304 doubles
};
// f32 offsets (float*), region starts at byte 65536
enum : int {
  F_M1   = 16384,  // 64
  F_R1   = 16448,  // 64
  F_M2   = 16512,  // 128
  F_R2   = 16640,  // 128
  F_M3   = 16768,  // 64
  F_R3   = 16832,  // 64
  F_W2T  = 16896,  // 8192 transposed w2 [c][o]
  F_W3T  = 25088,  // 8192 transposed w3 [o][q]
  F_TOPK = 33280,  // 2048*16 int32 -> ends float 66048 (byte 264192)
};
#define Y3_B     524288
#define S1PART_B 524288                      // overlays y3 (disjoint lifetime)
#define M1PART_B (524288 + GRID_COV * 4096 * 8)

// Faithful f32 layer-1 forward: identical expression in k_cov64 and k_fwd ->
// bit-identical h1 everywhere. Mirrors reference f32 op order.
__device__ __forceinline__ float h1_of(const float* __restrict__ w1,
                                       const float* __restrict__ b1,
                                       const float* __restrict__ g1,
                                       const float* __restrict__ be1,
                                       const float* __restrict__ fw, int c,
                                       float x0, float x1, float x2) {
  float s = w1[c*3+0] * x0;
  s = fmaf(w1[c*3+1], x1, s);
  s = fmaf(w1[c*3+2], x2, s);
  float y1 = s + b1[c];
  float t = y1 - fw[F_M1 + c];
  float u = t * fw[F_R1 + c];
  u = u * g1[c];
  u = u + be1[c];
  return fmaxf(u, 0.f);
}

// ---------------- K1: f64 mean + 3x3 second moment of x ----------------
__global__ __launch_bounds__(256) void k_xstats64(const float* __restrict__ x,
                                                  double* __restrict__ wd) {
  double a0=0,a1=0,a2=0,m00=0,m01=0,m02=0,m11=0,m12=0,m22=0;
  for (int p = blockIdx.x * 256 + threadIdx.x; p < NPTS; p += gridDim.x * 256) {
    int b = p >> 14, n = p & (N_ - 1);
    const float* xb = x + (size_t)b * 3 * N_ + n;
    double x0 = xb[0], x1 = xb[N_], x2 = xb[2 * N_];
    a0 += x0; a1 += x1; a2 += x2;
    m00 = fma(x0,x0,m00); m01 = fma(x0,x1,m01); m02 = fma(x0,x2,m02);
    m11 = fma(x1,x1,m11); m12 = fma(x1,x2,m12); m22 = fma(x2,x2,m22);
  }
  #pragma unroll
  for (int m = 32; m >= 1; m >>= 1) {
    a0 += __shfl_xor(a0, m); a1 += __shfl_xor(a1, m); a2 += __shfl_xor(a2, m);
    m00 += __shfl_xor(m00, m); m01 += __shfl_xor(m01, m); m02 += __shfl_xor(m02, m);
    m11 += __shfl_xor(m11, m); m12 += __shfl_xor(m12, m); m22 += __shfl_xor(m22, m);
  }
  if ((threadIdx.x & 63) == 0) {
    atomicAdd(&wd[D_X9+0], a0); atomicAdd(&wd[D_X9+1], a1); atomicAdd(&wd[D_X9+2], a2);
    atomicAdd(&wd[D_X9+3], m00); atomicAdd(&wd[D_X9+4], m01); atomicAdd(&wd[D_X9+5], m02);
    atomicAdd(&wd[D_X9+6], m11); atomicAdd(&wd[D_X9+7], m12); atomicAdd(&wd[D_X9+8], m22);
  }
}

// ---------------- K2: BN1 f32 coefficients from exact x-moments ----------------
__global__ void k_prep1(const float* __restrict__ w1, const float* __restrict__ b1,
                        double* __restrict__ wd, float* __restrict__ fw) {
  int c = threadIdx.x;
  if (c >= 64) return;
  const double inv = 1.0 / (double)NPTS;
  double mx0 = wd[0]*inv, mx1 = wd[1]*inv, mx2 = wd[2]*inv;
  double c00 = wd[3]*inv - mx0*mx0, c01 = wd[4]*inv - mx0*mx1, c02 = wd[5]*inv - mx0*mx2;
  double c11 = wd[6]*inv - mx1*mx1, c12 = wd[7]*inv - mx1*mx2, c22 = wd[8]*inv - mx2*mx2;
  double w0 = w1[c*3+0], w1_ = w1[c*3+1], w2_ = w1[c*3+2];
  double m1 = w0*mx0 + w1_*mx1 + w2_*mx2 + (double)b1[c];
  double var = w0*w0*c00 + w1_*w1_*c11 + w2_*w2_*c22
             + 2.0*(w0*w1_*c01 + w0*w2_*c02 + w1_*w2_*c12);
  fw[F_M1 + c] = (float)m1;
  float vpe = (float)var + 1e-5f;
  fw[F_R1 + c] = (float)(1.0 / sqrt((double)vpe));
}

// ------- K3: f64 second moment + sums of the ACTUAL f32 h1 values -------
__global__ __launch_bounds__(256) void k_cov64(const float* __restrict__ x,
                                               const float* __restrict__ w1,
                                               const float* __restrict__ b1,
                                               const float* __restrict__ g1,
                                               const float* __restrict__ be1,
                                               const float* __restrict__ fw,
                                               double* __restrict__ s1part,
                                               double* __restrict__ m1part) {
  __shared__ double tile[64 * 64];   // 32 KB: 64 points x 64 ch (f64 copies of f32 h1)
  const int tid = threadIdx.x;
  const int cover = tid >> 6, lane = tid & 63;
  const int ti = lane & 7, tj = lane >> 3;
  double acc[64];
  #pragma unroll
  for (int k = 0; k < 64; ++k) acc[k] = 0.0;
  double msum = 0.0;
  const int mc = tid & 63, mp0 = tid >> 6;

  for (int chunk = blockIdx.x; chunk < NPTS / 64; chunk += gridDim.x) {
    __syncthreads();
    {
      int pt = tid >> 2, q = tid & 3;
      int p = chunk * 64 + pt;
      int b = p >> 14, n = p & (N_ - 1);
      const float* xb = x + (size_t)b * 3 * N_ + n;
      float x0 = xb[0], x1 = xb[N_], x2 = xb[2 * N_];
      #pragma unroll
      for (int k = 0; k < 16; ++k) {
        int c = q * 16 + k;
        tile[pt * 64 + c] = (double)h1_of(w1, b1, g1, be1, fw, c, x0, x1, x2);
      }
    }
    __syncthreads();
    for (int pp = cover * 16; pp < cover * 16 + 16; ++pp) {
      const double* tp = tile + pp * 64;
      double a[8], bb[8];
      #pragma unroll
      for (int j = 0; j < 8; ++j) a[j] = tp[8 * ti + j];
      #pragma unroll
      for (int j = 0; j < 8; ++j) bb[j] = tp[8 * tj + j];
      #pragma unroll
      for (int r = 0; r < 8; ++r)
        #pragma unroll
        for (int q = 0; q < 8; ++q)
          acc[r*8+q] = fma(a[r], bb[q], acc[r*8+q]);
    }
    for (int pp = mp0; pp < 64; pp += 4) msum += tile[pp * 64 + mc];
  }
  __syncthreads();
  for (int cv = 0; cv < 4; ++cv) {
    if (cover == cv) {
      #pragma unroll
      for (int k = 0; k < 64; ++k) {
        int r = k >> 3, q = k & 7;
        int off = (8 * ti + r) * 64 + 8 * tj + q;
        if (cv == 0) tile[off] = acc[k]; else tile[off] += acc[k];
      }
    }
    __syncthreads();
  }
  for (int e = tid; e < 4096; e += 256) s1part[(size_t)blockIdx.x * 4096 + e] = tile[e];
  __syncthreads();
  tile[tid] = msum;
  __syncthreads();
  if (tid < 64)
    m1part[(size_t)blockIdx.x * 64 + tid] =
      tile[tid] + tile[64+tid] + tile[128+tid] + tile[192+tid];
}

// ---------------- K3b: sum partials ----------------
__global__ __launch_bounds__(256) void k_redS1(const double* __restrict__ s1part,
                                               const double* __restrict__ m1part,
                                               double* __restrict__ wd) {
  int tid = threadIdx.x;
  if (blockIdx.x < 16) {
    int e = blockIdx.x * 256 + tid;
    double s = 0.0;
    for (int b = 0; b < GRID_COV; ++b) s += s1part[(size_t)b * 4096 + e];
    wd[D_S1 + e] = s;
  } else if (tid < 64) {
    double s = 0.0;
    for (int b = 0; b < GRID_COV; ++b) s += m1part[(size_t)b * 64 + tid];
    wd[D_MEAN1 + tid] = s;
  }
}

// ------- K4: BN2 f32 coefficients + w2 transpose + w3 transpose -------
__global__ __launch_bounds__(64) void k_prep2(const float* __restrict__ w2,
                                              const float* __restrict__ b2,
                                              const float* __restrict__ w3,
                                              double* __restrict__ wd,
                                              float* __restrict__ fw) {
  __shared__ double r1[64], r2[64];
  const int o = blockIdx.x, c = threadIdx.x;
  double wv = (double)w2[o * 64 + c];
  double inner = 0.0;
  for (int cc = 0; cc < 64; ++cc)
    inner = fma(wd[D_S1 + c * 64 + cc], (double)w2[o * 64 + cc], inner);
  r1[c] = wv * inner;
  r2[c] = wv * wd[D_MEAN1 + c];
  __syncthreads();
  for (int st = 32; st > 0; st >>= 1) {
    if (c < st) { r1[c] += r1[c + st]; r2[c] += r2[c + st]; }
    __syncthreads();
  }
  if (c == 0) {
    const double inv = 1.0 / (double)NPTS;
    double mraw = r2[0] * inv;
    double var = r1[0] * inv - mraw * mraw;
    fw[F_M2 + o] = (float)(mraw + (double)b2[o]);
    float vpe = (float)var + 1e-5f;
    fw[F_R2 + o] = (float)(1.0 / sqrt((double)vpe));
  }
  fw[F_W2T + c * 128 + o] = w2[o * 64 + c];      // [c][o]
  fw[F_W3T + o * 64 + c] = w3[c * 128 + o];      // [o][q] (q = c here, o = 0..127)
}

// -------- K5: cooperative 64-point LDS-tile forward (bit-identical math) --------
// Phase1: h1 -> LDS [c][p]. Phase2: wave-owned o-chunk(32), acc in regs,
// weights via uniform s_loads. Phase3: wave-owned q-chunk(16). Same fmaf
// chain order per output as the R3-passing per-thread kernel.
__global__ __launch_bounds__(256, 3) void k_fwd(const float* __restrict__ x,
                                                const float* __restrict__ w1,
                                                const float* __restrict__ b1,
                                                const float* __restrict__ g1,
                                                const float* __restrict__ be1,
                                                const float* __restrict__ b2,
                                                const float* __restrict__ g2,
                                                const float* __restrict__ be2,
                                                const float* __restrict__ b3,
                                                const float* __restrict__ fw,
                                                float* __restrict__ y3out) {
  __shared__ float h1s[64 * 64];    // [c][p] 16 KB
  __shared__ float h2s[128 * 64];   // [o][p] 32 KB
  const int tid = threadIdx.x;
  const int lane = tid & 63;
  const int wvu = __builtin_amdgcn_readfirstlane(tid >> 6);
  const int p = blockIdx.x * 64 + lane;
  const int b = p >> 14, n = p & (N_ - 1);
  const float* xb = x + (size_t)b * 3 * N_ + n;
  const float x0 = xb[0], x1 = xb[N_], x2 = xb[2 * N_];

  // phase 1: this wave computes c in [wvu*16, wvu*16+16) for its lane's point
  #pragma unroll
  for (int k = 0; k < 16; ++k) {
    int c = wvu * 16 + k;
    h1s[c * 64 + lane] = h1_of(w1, b1, g1, be1, fw, c, x0, x1, x2);
  }
  __syncthreads();

  // phase 2: o-chunk of 32 per wave
  {
    const float* w2t = fw + F_W2T;
    const int o0 = wvu * 32;
    float acc[32];
    #pragma unroll
    for (int j = 0; j < 32; ++j) acc[j] = 0.f;
    #pragma unroll 4
    for (int c = 0; c < 64; ++c) {
      float hc = h1s[c * 64 + lane];
      const float* wc = w2t + c * 128 + o0;
      #pragma unroll
      for (int j = 0; j < 32; ++j) acc[j] = fmaf(wc[j], hc, acc[j]);
    }
    #pragma unroll
    for (int j = 0; j < 32; ++j) {
      int o = o0 + j;
      float y2 = acc[j] + b2[o];
      float t = y2 - fw[F_M2 + o];
      float u = t * fw[F_R2 + o];
      u = u * g2[o];
      u = u + be2[o];
      h2s[o * 64 + lane] = fmaxf(u, 0.f);
    }
  }
  __syncthreads();

  // phase 3: q-chunk of 16 per wave
  {
    const float* w3t = fw + F_W3T;
    const int q0 = wvu * 16;
    float a3[16];
    {
      float h0 = h2s[0 * 64 + lane];
      const float* wr = w3t + 0 * 64 + q0;
      #pragma unroll
      for (int j = 0; j < 16; ++j) a3[j] = wr[j] * h0;
    }
    #pragma unroll 4
    for (int o = 1; o < 128; ++o) {
      float ho = h2s[o * 64 + lane];
      const float* wr = w3t + o * 64 + q0;
      #pragma unroll
      for (int j = 0; j < 16; ++j) a3[j] = fmaf(wr[j], ho, a3[j]);
    }
    float* yrow = y3out + (size_t)b * 64 * N_ + n;
    #pragma unroll
    for (int j = 0; j < 16; ++j) {
      int q = q0 + j;
      yrow[(size_t)q * N_] = a3[j] + b3[q];
    }
  }
}

__global__ void k_prep3(double* __restrict__ wd, float* __restrict__ fw) {
  int o = threadIdx.x;
  if (o >= 64) return;
  const double inv = 1.0 / (double)NPTS;
  double m = wd[D_Y3SUM + o] * inv;
  double var = wd[D_Y3SQ + o] * inv - m * m;
  fw[F_M3 + o] = (float)m;
  float vpe = (float)var + 1e-5f;
  fw[F_R3 + o] = (float)(1.0 / sqrt((double)vpe));
}

// -------- K6: top-16 of sgn(g3)*y3 per (b,c) row, FUSED with y3 channel stats --------
// Stats arithmetic replicates the removed k_y3stats exactly (same per-thread
// order, same 256-tree reduce, same atomicAdd) -> bit-identical M3/R3.
__global__ __launch_bounds__(256) void k_topk(const float* __restrict__ y3,
                                              const float* __restrict__ g3,
                                              int* __restrict__ topk,
                                              double* __restrict__ wd) {
  __shared__ float sval[256 * 16];
  __shared__ int   sidx[256 * 16];
  __shared__ double ssum[256], ssq[256];
  const int tid = threadIdx.x;
  const int row = blockIdx.x;
  const int c = row & 63;
  const float sgn = (g3[c] >= 0.f) ? 1.f : -1.f;
  const float4* y = (const float4*)(y3 + (size_t)row * N_);
  float val[16]; int idx[16];
  #pragma unroll
  for (int k = 0; k < 16; ++k) { val[k] = 3.0e38f; idx[k] = 0x7fffffff; }
  auto ins = [&](float v, int i) {
    if (v < val[15] || (v == val[15] && i < idx[15])) {
      float cv = v; int ci = i;
      #pragma unroll
      for (int k = 0; k < 16; ++k) {
        bool sw = (cv < val[k]) || (cv == val[k] && ci < idx[k]);
        float tv = val[k]; int tj = idx[k];
        if (sw) { val[k] = cv; idx[k] = ci; cv = tv; ci = tj; }
      }
    }
  };
  double s = 0.0, q = 0.0;
  #pragma unroll 1
  for (int it = 0; it < 16; ++it) {
    int n4 = it * 256 + tid;
    float4 v = y[n4];
    int nb = n4 * 4;
    {
      double a = v.x, bb = v.y, cc2 = v.z, d = v.w;
      s += a + bb + cc2 + d;
      q = fma(a,a,q); q = fma(bb,bb,q); q = fma(cc2,cc2,q); q = fma(d,d,q);
    }
    ins(sgn * v.x, nb + 0);
    ins(sgn * v.y, nb + 1);
    ins(sgn * v.z, nb + 2);
    ins(sgn * v.w, nb + 3);
  }
  ssum[tid] = s; ssq[tid] = q;
  #pragma unroll
  for (int k = 0; k < 16; ++k) { sval[tid*16+k] = val[k]; sidx[tid*16+k] = idx[k]; }
  __syncthreads();
  for (int st = 128; st > 0; st >>= 1) {
    if (tid < st) { ssum[tid] += ssum[tid + st]; ssq[tid] += ssq[tid + st]; }
    __syncthreads();
  }
  if (tid == 0) {
    atomicAdd(&wd[D_Y3SUM + c], ssum[0]);
    atomicAdd(&wd[D_Y3SQ  + c], ssq[0]);
  }
  for (int st2 = 1; st2 < 256; st2 <<= 1) {
    if ((tid & (2 * st2 - 1)) == 0) {
      int pa = tid * 16, pb = (tid + st2) * 16;
      int ia = 0, ib = 0;
      float mv[16]; int mi[16];
      #pragma unroll
      for (int k = 0; k < 16; ++k) {
        float va = sval[pa + ia]; int ja = sidx[pa + ia];
        float vb = sval[pb + ib]; int jb = sidx[pb + ib];
        bool ta = (va < vb) || (va == vb && ja < jb);
        mv[k] = ta ? va : vb; mi[k] = ta ? ja : jb;
        if (ta) ++ia; else ++ib;
      }
      #pragma unroll
      for (int k = 0; k < 16; ++k) { sval[pa + k] = mv[k]; sidx[pa + k] = mi[k]; }
    }
    __syncthreads();
  }
  if (tid < 16) topk[row * 16 + tid] = sidx[tid];
}

// ---------------- K7: gather feat (faithful BN3 apply) + idx as float ----------------
__global__ __launch_bounds__(256) void k_gather(const float* __restrict__ x,
                                                const float* __restrict__ fw,
                                                const float* __restrict__ g3,
                                                const float* __restrict__ be3,
                                                const float* __restrict__ y3,
                                                const int* __restrict__ topk,
                                                float* __restrict__ out) {
  __shared__ int s_i[16];
  __shared__ float s_m[64], s_r[64], s_g[64], s_b[64];
  const int tid = threadIdx.x;
  const int row = blockIdx.x;
  const int b = row >> 6, c = row & 63;
  if (tid < 16) s_i[tid] = topk[row * 16 + tid];
  if (tid < 64) {
    s_m[tid] = fw[F_M3 + tid]; s_r[tid] = fw[F_R3 + tid];
    s_g[tid] = g3[tid];        s_b[tid] = be3[tid];
  }
  __syncthreads();
  for (int t = tid; t < 67 * 16; t += 256) {
    int ch = t >> 4, n = t & 15, i = s_i[n];
    float v;
    if (ch < 3) {
      v = x[((size_t)b * 3 + ch) * N_ + i];
    } else {
      int c2 = ch - 3;
      float yv = y3[((size_t)b * 64 + c2) * N_ + i];
      float tt = yv - s_m[c2];
      float u = tt * s_r[c2];
      u = u * s_g[c2];
      v = u + s_b[c2];
    }
    out[(((size_t)b * 67 + ch) * 64 + c) * 16 + n] = v;
  }
  if (tid < 48) {
    int ch = tid >> 4, n = tid & 15;
    out[FEATSZ + (((size_t)b * 3 + ch) * 64 + c) * 16 + n] = (float)s_i[n];
  }
}

extern "C" void kernel_launch(void* const* d_in, const int* in_sizes, int n_in,
                              void* d_out, int out_size, void* d_ws, size_t ws_size,
                              hipStream_t stream) {
  const float* x   = (const float*)d_in[0];
  const float* w1  = (const float*)d_in[1];
  const float* b1  = (const float*)d_in[2];
  const float* g1  = (const float*)d_in[3];
  const float* be1 = (const float*)d_in[4];
  const float* w2  = (const float*)d_in[5];
  const float* b2  = (const float*)d_in[6];
  const float* g2  = (const float*)d_in[7];
  const float* be2 = (const float*)d_in[8];
  const float* w3  = (const float*)d_in[9];
  const float* b3  = (const float*)d_in[10];
  const float* g3  = (const float*)d_in[11];
  const float* be3 = (const float*)d_in[12];
  double* wd = (double*)d_ws;
  float*  fw = (float*)d_ws;
  float*  out = (float*)d_out;
  int* topk = (int*)(fw + F_TOPK);
  double* s1part = (double*)((char*)d_ws + S1PART_B);
  double* m1part = (double*)((char*)d_ws + M1PART_B);
  float*  y3     = (float*)((char*)d_ws + Y3_B);

  hipMemsetAsync(d_ws, 0, 1216, stream);   // zero D_X9 + D_Y3SUM + D_Y3SQ
  k_xstats64<<<512, 256, 0, stream>>>(x, wd);
  k_prep1   <<<1, 64, 0, stream>>>(w1, b1, wd, fw);
  k_cov64   <<<GRID_COV, 256, 0, stream>>>(x, w1, b1, g1, be1, fw, s1part, m1part);
  k_redS1   <<<17, 256, 0, stream>>>(s1part, m1part, wd);
  k_prep2   <<<128, 64, 0, stream>>>(w2, b2, w3, wd, fw);
  k_fwd     <<<NPTS / 64, 256, 0, stream>>>(x, w1, b1, g1, be1, b2, g2, be2, b3, fw, y3);
  k_topk    <<<B_ * 64, 256, 0, stream>>>(y3, g3, topk, wd);
  k_prep3   <<<1, 64, 0, stream>>>(wd, fw);
  k_gather  <<<B_ * 64, 256, 0, stream>>>(x, fw, g3, be3, y3, topk, out);
  (void)in_sizes; (void)n_in; (void)out_size; (void)ws_size;
}